// Round 1
// baseline (78048.352 us; speedup 1.0000x reference)
//
#include <hip/hip_runtime.h>
#include <hip/hip_bf16.h>

#define S_LEN 4096
#define IDIM  2048
#define HDIM  2048
#define G4    (4 * HDIM)   // 8192 gate rows

// ---- bf16 helpers (bit-level, no API ambiguity) ----
__device__ __forceinline__ unsigned short f2bf(float f) {
  unsigned u = __float_as_uint(f);
  unsigned r = (u + 0x7FFFu + ((u >> 16) & 1u)) >> 16;   // RNE
  return (unsigned short)r;
}
__device__ __forceinline__ float bf2f(unsigned short h) {
  return __uint_as_float(((unsigned)h) << 16);
}

// =====================================================================
// Kernel 1: xg[s][G] = x[s,:]·W_ih[G,:] + b_ih[G] + b_hh[G]   (store bf16)
// fp32, 64x64 tile, K-step 16, 256 threads, transposed LDS tiles.
// =====================================================================
#define TS 64
#define KS 16
__global__ __launch_bounds__(256) void gemm_xg(
    const float* __restrict__ x, const float* __restrict__ Wih,
    const float* __restrict__ bih, const float* __restrict__ bhh,
    unsigned short* __restrict__ xg) {
  __shared__ float At[KS][TS + 4];
  __shared__ float Bt[KS][TS + 4];
  const int t  = threadIdx.x;
  const int tx = t & 15, ty = t >> 4;
  const int s0 = blockIdx.y * TS, j0 = blockIdx.x * TS;
  const int lrow = t >> 2, lk4 = (t & 3) * 4;
  float acc[4][4] = {};

  for (int k0 = 0; k0 < IDIM; k0 += KS) {
    const float4 av = *(const float4*)&x  [(size_t)(s0 + lrow) * IDIM + k0 + lk4];
    const float4 bv = *(const float4*)&Wih[(size_t)(j0 + lrow) * IDIM + k0 + lk4];
    __syncthreads();                       // protect prior iter's reads
    At[lk4+0][lrow] = av.x; At[lk4+1][lrow] = av.y;
    At[lk4+2][lrow] = av.z; At[lk4+3][lrow] = av.w;
    Bt[lk4+0][lrow] = bv.x; Bt[lk4+1][lrow] = bv.y;
    Bt[lk4+2][lrow] = bv.z; Bt[lk4+3][lrow] = bv.w;
    __syncthreads();
#pragma unroll
    for (int k = 0; k < KS; ++k) {
      float a[4], bb[4];
      *(float4*)a  = *(const float4*)&At[k][ty * 4];
      *(float4*)bb = *(const float4*)&Bt[k][tx * 4];
#pragma unroll
      for (int i = 0; i < 4; ++i)
#pragma unroll
        for (int j = 0; j < 4; ++j)
          acc[i][j] = fmaf(a[i], bb[j], acc[i][j]);
    }
  }
  const float4 b1 = *(const float4*)&bih[j0 + tx * 4];
  const float4 b2 = *(const float4*)&bhh[j0 + tx * 4];
  const float bias[4] = {b1.x + b2.x, b1.y + b2.y, b1.z + b2.z, b1.w + b2.w};
#pragma unroll
  for (int i = 0; i < 4; ++i) {
    ushort4 pk;
    pk.x = f2bf(acc[i][0] + bias[0]);
    pk.y = f2bf(acc[i][1] + bias[1]);
    pk.z = f2bf(acc[i][2] + bias[2]);
    pk.w = f2bf(acc[i][3] + bias[3]);
    *(ushort4*)&xg[(size_t)(s0 + ty * 4 + i) * G4 + j0 + tx * 4] = pk;
  }
}

// =====================================================================
// Kernel 2: persistent cooperative scan. 256 blocks x 512 threads.
// Block b owns hidden units [b*8, b*8+8) -> gate rows {g*2048 + b*8 + u}.
// Thread (r = tid&31, c = tid>>5): gate row r's k-chunk [c*128, c*128+128)
// of W_hh held in 128 fp32 REGISTERS for all 4096 steps.
// h_t lives in d_out (it IS the output); per-block flag = steps completed.
// =====================================================================
#define NB  256
#define TPB 512
__global__ __launch_bounds__(TPB) void lstm_scan(
    const unsigned short* __restrict__ xg, const float* __restrict__ Whh,
    const float* __restrict__ h0, const float* __restrict__ c0,
    float* __restrict__ out, unsigned* __restrict__ flags) {
  __shared__ float h_sh[HDIM];
  __shared__ float part[16][33];
  __shared__ float gact[32];
  __shared__ float c_sh[8];

  const int b = blockIdx.x, t = threadIdx.x;
  const int r = t & 31, c = t >> 5;        // r: local gate row, c: k-chunk
  const int g = r >> 3, u = r & 7;
  const size_t row_g = (size_t)g * HDIM + b * 8 + u;

  // one-time W_hh chunk -> registers (fp32, statically indexed)
  float w[128];
  const float* wp = Whh + row_g * HDIM + c * 128;
#pragma unroll
  for (int i = 0; i < 32; ++i) {
    const float4 v = *(const float4*)(wp + i * 4);
    w[i*4+0] = v.x; w[i*4+1] = v.y; w[i*4+2] = v.z; w[i*4+3] = v.w;
  }
  if (t < 8) c_sh[t] = c0[b * 8 + t];
  __syncthreads();

  for (int ts = 0; ts < S_LEN; ++ts) {
    // prefetch my xg value early (hides L3/HBM latency behind the wait)
    float xgv = 0.f;
    if (t < 32)
      xgv = bf2f(xg[(size_t)ts * G4 + (size_t)(t >> 3) * HDIM + b * 8 + (t & 7)]);

    // 1. wait until every block has published h_{ts-1}
    if (ts > 0 && t < 64) {
      for (int i = t; i < NB; i += 64) {
        while (__hip_atomic_load(&flags[i], __ATOMIC_ACQUIRE,
                                 __HIP_MEMORY_SCOPE_AGENT) < (unsigned)ts) {}
      }
    }
    __syncthreads();

    // 2. stage h_{ts-1} into LDS (agent-scope loads bypass stale caches)
    const float* hsrc = (ts == 0) ? h0 : out + (size_t)(ts - 1) * HDIM;
    for (int i = t; i < HDIM; i += TPB)
      h_sh[i] = __hip_atomic_load(&hsrc[i], __ATOMIC_RELAXED,
                                  __HIP_MEMORY_SCOPE_AGENT);
    __syncthreads();

    // 3. partial dot: 128 MACs from registers vs broadcast LDS h
    float acc = 0.f;
    const float4* h4 = (const float4*)&h_sh[c * 128];
#pragma unroll
    for (int i = 0; i < 32; ++i) {
      const float4 hv = h4[i];
      acc = fmaf(w[i*4+0], hv.x, acc);
      acc = fmaf(w[i*4+1], hv.y, acc);
      acc = fmaf(w[i*4+2], hv.z, acc);
      acc = fmaf(w[i*4+3], hv.w, acc);
    }
    part[c][r] = acc;
    __syncthreads();

    // 4. reduce 16 partials per row, add xg, activate
    if (t < 32) {
      float s = xgv;
#pragma unroll
      for (int i = 0; i < 16; ++i) s += part[i][t];
      gact[t] = ((t >> 3) == 2) ? tanhf(s) : 1.f / (1.f + __expf(-s));
    }
    __syncthreads();

    // 5. cell/hidden update for this block's 8 units; publish h
    if (t < 8) {
      const float iv = gact[ 0 + t], fv = gact[ 8 + t];
      const float gv = gact[16 + t], ov = gact[24 + t];
      const float cn = fmaf(fv, c_sh[t], iv * gv);
      c_sh[t] = cn;
      const float hn = ov * tanhf(cn);
      __hip_atomic_store(&out[(size_t)ts * HDIM + b * 8 + t], hn,
                         __ATOMIC_RELAXED, __HIP_MEMORY_SCOPE_AGENT);
    }
    __syncthreads();          // wave0's vmcnt(0) drains the h stores
    if (t == 0) {
      __threadfence();
      __hip_atomic_store(&flags[b], (unsigned)(ts + 1),
                         __ATOMIC_RELEASE, __HIP_MEMORY_SCOPE_AGENT);
    }
  }
}

// =====================================================================
extern "C" void kernel_launch(void* const* d_in, const int* in_sizes, int n_in,
                              void* d_out, int out_size, void* d_ws, size_t ws_size,
                              hipStream_t stream) {
  const float* x   = (const float*)d_in[0];
  const float* Wih = (const float*)d_in[1];
  const float* Whh = (const float*)d_in[2];
  const float* bih = (const float*)d_in[3];
  const float* bhh = (const float*)d_in[4];
  const float* h0  = (const float*)d_in[5];
  const float* c0  = (const float*)d_in[6];
  float* out = (float*)d_out;

  unsigned short* xg = (unsigned short*)d_ws;                       // 64 MB bf16
  unsigned* flags = (unsigned*)((char*)d_ws +
                    (size_t)S_LEN * G4 * sizeof(unsigned short));

  hipMemsetAsync(flags, 0, NB * sizeof(unsigned), stream);

  dim3 g1(G4 / TS, S_LEN / TS);
  gemm_xg<<<g1, 256, 0, stream>>>(x, Wih, bih, bhh, xg);

  void* args[] = {(void*)&xg, (void*)&Whh, (void*)&h0,
                  (void*)&c0, (void*)&out, (void*)&flags};
  hipLaunchCooperativeKernel((void*)lstm_scan, dim3(NB), dim3(TPB),
                             args, 0, stream);
}

// Round 2
// 13413.739 us; speedup vs baseline: 5.8185x; 5.8185x over previous
//
#include <hip/hip_runtime.h>
#include <hip/hip_bf16.h>

#define S_LEN 4096
#define IDIM  2048
#define HDIM  2048
#define G4    8192
#define NB    256
#define TPB   512

// ---- bf16 helpers ----
__device__ __forceinline__ unsigned short f2bf(float f) {
  unsigned u = __float_as_uint(f);
  unsigned r = (u + 0x7FFFu + ((u >> 16) & 1u)) >> 16;   // RNE
  return (unsigned short)r;
}
__device__ __forceinline__ float bf2f(unsigned short h) {
  return __uint_as_float(((unsigned)h) << 16);
}

__device__ __forceinline__ unsigned long long pack_rec(float h, unsigned tag) {
  return (unsigned long long)__float_as_uint(h) | ((unsigned long long)tag << 32);
}

// =====================================================================
// Kernel 1: xg[s][G] = x[s,:]·W_ih[G,:] + b_ih[G] + b_hh[G]   (store bf16)
// (unchanged from round 1 — passed; ~4.5 ms. MFMA rewrite next round.)
// =====================================================================
#define TS 64
#define KS 16
__global__ __launch_bounds__(256) void gemm_xg(
    const float* __restrict__ x, const float* __restrict__ Wih,
    const float* __restrict__ bih, const float* __restrict__ bhh,
    unsigned short* __restrict__ xg) {
  __shared__ float At[KS][TS + 4];
  __shared__ float Bt[KS][TS + 4];
  const int t  = threadIdx.x;
  const int tx = t & 15, ty = t >> 4;
  const int s0 = blockIdx.y * TS, j0 = blockIdx.x * TS;
  const int lrow = t >> 2, lk4 = (t & 3) * 4;
  float acc[4][4] = {};

  for (int k0 = 0; k0 < IDIM; k0 += KS) {
    const float4 av = *(const float4*)&x  [(size_t)(s0 + lrow) * IDIM + k0 + lk4];
    const float4 bv = *(const float4*)&Wih[(size_t)(j0 + lrow) * IDIM + k0 + lk4];
    __syncthreads();
    At[lk4+0][lrow] = av.x; At[lk4+1][lrow] = av.y;
    At[lk4+2][lrow] = av.z; At[lk4+3][lrow] = av.w;
    Bt[lk4+0][lrow] = bv.x; Bt[lk4+1][lrow] = bv.y;
    Bt[lk4+2][lrow] = bv.z; Bt[lk4+3][lrow] = bv.w;
    __syncthreads();
#pragma unroll
    for (int k = 0; k < KS; ++k) {
      float a[4], bb[4];
      *(float4*)a  = *(const float4*)&At[k][ty * 4];
      *(float4*)bb = *(const float4*)&Bt[k][tx * 4];
#pragma unroll
      for (int i = 0; i < 4; ++i)
#pragma unroll
        for (int j = 0; j < 4; ++j)
          acc[i][j] = fmaf(a[i], bb[j], acc[i][j]);
    }
  }
  const float4 b1 = *(const float4*)&bih[j0 + tx * 4];
  const float4 b2 = *(const float4*)&bhh[j0 + tx * 4];
  const float bias[4] = {b1.x + b2.x, b1.y + b2.y, b1.z + b2.z, b1.w + b2.w};
#pragma unroll
  for (int i = 0; i < 4; ++i) {
    ushort4 pk;
    pk.x = f2bf(acc[i][0] + bias[0]);
    pk.y = f2bf(acc[i][1] + bias[1]);
    pk.z = f2bf(acc[i][2] + bias[2]);
    pk.w = f2bf(acc[i][3] + bias[3]);
    *(ushort4*)&xg[(size_t)(s0 + ty * 4 + i) * G4 + j0 + tx * 4] = pk;
  }
}

// =====================================================================
// Kernel 2: persistent cooperative scan, fence-free tagged-record sync.
//
// rec = 2-slot ring of 2048 8-byte records {fp32 h, u32 tag}.
//   step ts publishes h_ts with tag=ts+1 into slot (ts+1)&1  (8 relaxed
//   8B atomic stores per block; atomic => tag+data indivisible).
//   step ts consumes h_{ts-1}: polls slot ts&1 until tag==ts.
// Overwrite safety: a block reaches publish(ts+1) only after consuming
// all tag-ts records, which requires every block published tag ts,
// which requires every block consumed all tag-(ts-1) records — the
// records that publish(ts+1) overwrites. QED.
// No acquire/release/fences anywhere => no buffer_inv / buffer_wbl2.
// =====================================================================
__global__ __launch_bounds__(TPB, 2) void lstm_scan(
    const unsigned short* __restrict__ xg, const float* __restrict__ Whh,
    const float* __restrict__ h0, const float* __restrict__ c0,
    float* __restrict__ out, unsigned long long* __restrict__ rec) {
  __shared__ float h_sh[2][HDIM];
  __shared__ float part[16][33];

  const int b = blockIdx.x, t = threadIdx.x;
  const int r = t & 31, c = t >> 5;        // r: local gate row, c: k-chunk
  const size_t row_g = (size_t)(r >> 3) * HDIM + b * 8 + (r & 7);

  // one-time W_hh chunk -> 128 fp32 registers (launch_bounds(512,2)
  // gives the allocator a 256-VGPR budget so this must not spill)
  float w[128];
  {
    const float* wp = Whh + row_g * HDIM + c * 128;
#pragma unroll
    for (int i = 0; i < 32; ++i) {
      const float4 v = *(const float4*)(wp + i * 4);
      w[i*4+0] = v.x; w[i*4+1] = v.y; w[i*4+2] = v.z; w[i*4+3] = v.w;
    }
  }
  float c_reg = (t < 8) ? c0[b * 8 + t] : 0.f;

  for (int ts = 0; ts < S_LEN; ++ts) {
    const int buf = ts & 1;
    // xg prefetch for the reduce wave (latency hides under the poll)
    float xgv = 0.f;
    if (t < 32)
      xgv = bf2f(xg[(size_t)ts * G4 + (size_t)(t >> 3) * HDIM + b * 8 + (t & 7)]);

    // ---- acquire h_{ts-1} ----
    if (ts == 0) {
      h_sh[0][t]        = h0[t];
      h_sh[0][t + 512]  = h0[t + 512];
      h_sh[0][t + 1024] = h0[t + 1024];
      h_sh[0][t + 1536] = h0[t + 1536];
    } else {
      const unsigned want = (unsigned)ts;
      const unsigned long long* slot = rec + (size_t)(ts & 1) * HDIM;
      unsigned long long r0, r1, r2, r3;
      for (;;) {
        r0 = __hip_atomic_load(slot + t,        __ATOMIC_RELAXED, __HIP_MEMORY_SCOPE_AGENT);
        r1 = __hip_atomic_load(slot + t + 512,  __ATOMIC_RELAXED, __HIP_MEMORY_SCOPE_AGENT);
        r2 = __hip_atomic_load(slot + t + 1024, __ATOMIC_RELAXED, __HIP_MEMORY_SCOPE_AGENT);
        r3 = __hip_atomic_load(slot + t + 1536, __ATOMIC_RELAXED, __HIP_MEMORY_SCOPE_AGENT);
        if ((unsigned)(r0 >> 32) == want && (unsigned)(r1 >> 32) == want &&
            (unsigned)(r2 >> 32) == want && (unsigned)(r3 >> 32) == want)
          break;
        __builtin_amdgcn_s_sleep(2);
      }
      h_sh[buf][t]        = __uint_as_float((unsigned)r0);
      h_sh[buf][t + 512]  = __uint_as_float((unsigned)r1);
      h_sh[buf][t + 1024] = __uint_as_float((unsigned)r2);
      h_sh[buf][t + 1536] = __uint_as_float((unsigned)r3);
    }
    __syncthreads();                       // h_sh[buf] ready

    // ---- partial dot: 128 register MACs vs broadcast LDS h ----
    float acc = 0.f;
    const float4* h4 = (const float4*)&h_sh[buf][c * 128];
#pragma unroll
    for (int i = 0; i < 32; ++i) {
      const float4 hv = h4[i];
      acc = fmaf(w[i*4+0], hv.x, acc);
      acc = fmaf(w[i*4+1], hv.y, acc);
      acc = fmaf(w[i*4+2], hv.z, acc);
      acc = fmaf(w[i*4+3], hv.w, acc);
    }
    part[c][r] = acc;
    __syncthreads();                       // part ready

    // ---- wave 0: reduce + activations + cell update + publish ----
    if (t < 64) {
      float gval = 0.f;
      if (t < 32) {
        float s = xgv;
#pragma unroll
        for (int i = 0; i < 16; ++i) s += part[i][t];
        gval = ((t >> 3) == 2) ? tanhf(s) : 1.f / (1.f + __expf(-s));
      }
      const float iv = __shfl(gval, (t & 7));
      const float fv = __shfl(gval, (t & 7) + 8);
      const float gv = __shfl(gval, (t & 7) + 16);
      const float ov = __shfl(gval, (t & 7) + 24);
      if (t < 8) {
        c_reg = fmaf(fv, c_reg, iv * gv);
        const float hn = ov * tanhf(c_reg);
        const int j = b * 8 + t;
        out[(size_t)ts * HDIM + j] = hn;
        __hip_atomic_store(&rec[(size_t)((ts + 1) & 1) * HDIM + j],
                           pack_rec(hn, (unsigned)(ts + 1)),
                           __ATOMIC_RELAXED, __HIP_MEMORY_SCOPE_AGENT);
      }
    }
    // no end-of-step barrier: next poll writes h_sh[buf^1]; part[] writes
    // for ts+1 are gated by the next __syncthreads.
  }
}

// =====================================================================
extern "C" void kernel_launch(void* const* d_in, const int* in_sizes, int n_in,
                              void* d_out, int out_size, void* d_ws, size_t ws_size,
                              hipStream_t stream) {
  const float* x   = (const float*)d_in[0];
  const float* Wih = (const float*)d_in[1];
  const float* Whh = (const float*)d_in[2];
  const float* bih = (const float*)d_in[3];
  const float* bhh = (const float*)d_in[4];
  const float* h0  = (const float*)d_in[5];
  const float* c0  = (const float*)d_in[6];
  float* out = (float*)d_out;

  // ws layout: [0,32KB) tagged-record ring | [32KB, 32KB+64MB) xg bf16
  unsigned long long* rec = (unsigned long long*)d_ws;
  unsigned short* xg = (unsigned short*)((char*)d_ws + 32768);

  hipMemsetAsync(rec, 0, 2 * HDIM * sizeof(unsigned long long), stream);

  dim3 g1(G4 / TS, S_LEN / TS);
  gemm_xg<<<g1, 256, 0, stream>>>(x, Wih, bih, bhh, xg);

  void* args[] = {(void*)&xg, (void*)&Whh, (void*)&h0,
                  (void*)&c0, (void*)&out, (void*)&rec};
  hipLaunchCooperativeKernel((void*)lstm_scan, dim3(NB), dim3(TPB),
                             args, 0, stream);
}

// Round 3
// 12781.580 us; speedup vs baseline: 6.1063x; 1.0495x over previous
//
#include <hip/hip_runtime.h>
#include <hip/hip_bf16.h>

#define S_LEN 4096
#define IDIM  2048
#define HDIM  2048
#define G4    8192
#define NB    256
#define TPB   512

typedef __attribute__((ext_vector_type(8))) short     bf16x8;
typedef __attribute__((ext_vector_type(4))) float     f32x4;

// ---- bf16 helpers ----
__device__ __forceinline__ unsigned short f2bf(float f) {
  unsigned u = __float_as_uint(f);
  unsigned r = (u + 0x7FFFu + ((u >> 16) & 1u)) >> 16;   // RNE
  return (unsigned short)r;
}
__device__ __forceinline__ float bf2f(unsigned short h) {
  return __uint_as_float(((unsigned)h) << 16);
}
__device__ __forceinline__ unsigned long long pack_rec(float h, unsigned tag) {
  return (unsigned long long)__float_as_uint(h) | ((unsigned long long)tag << 32);
}

// =====================================================================
// Kernel 1: xg = x·W_ihᵀ + b_ih + b_hh, bf16 MFMA.
// 128x128 tile, BK=32 (one 16x16x32 per K-step per frag), 4 waves in 2x2,
// reg-staged fp32->bf16 conversion (inputs are fp32; no extra ws pass).
// =====================================================================
#define BM 128
#define BKK 32
#define LDK 40   // padded LDS row (bf16 units): 80B, 16B-aligned rows

__global__ __launch_bounds__(256) void gemm_xg_mfma(
    const float* __restrict__ x, const float* __restrict__ Wih,
    const float* __restrict__ bih, const float* __restrict__ bhh,
    unsigned short* __restrict__ xg) {
  __shared__ unsigned short As[BM][LDK];
  __shared__ unsigned short Bs[BM][LDK];

  const int t = threadIdx.x;
  const int lane = t & 63, wid = t >> 6;
  const int wr = wid >> 1, wc = wid & 1;           // 2x2 wave grid

  // XCD-chunked bijective swizzle (2048 % 8 == 0)
  int bid = ((int)blockIdx.x & 7) * 256 + ((int)blockIdx.x >> 3);
  const int s0 = (bid >> 6) * BM;                  // 32 s-tiles
  const int j0 = (bid & 63) * BM;                  // 64 j-tiles

  f32x4 acc[4][4] = {};

  // per-lane bias for the 4 n-frags (C/D col = lane&15)
  float bias[4];
#pragma unroll
  for (int n = 0; n < 4; ++n) {
    const int col = j0 + wc * 64 + n * 16 + (lane & 15);
    bias[n] = bih[col] + bhh[col];
  }

  for (int k0 = 0; k0 < IDIM; k0 += BKK) {
    // stage: thread t covers float4-index f = t + 256u  (row=f>>3, kc=(f&7)*4)
    float4 va[4], vb[4];
#pragma unroll
    for (int u = 0; u < 4; ++u) {
      const int f = t + 256 * u;
      const int row = f >> 3, kc = (f & 7) * 4;
      va[u] = *(const float4*)&x  [(size_t)(s0 + row) * IDIM + k0 + kc];
      vb[u] = *(const float4*)&Wih[(size_t)(j0 + row) * IDIM + k0 + kc];
    }
    __syncthreads();                               // prior frag reads done
#pragma unroll
    for (int u = 0; u < 4; ++u) {
      const int f = t + 256 * u;
      const int row = f >> 3, kc = (f & 7) * 4;
      ushort4 pa, pb;
      pa.x = f2bf(va[u].x); pa.y = f2bf(va[u].y);
      pa.z = f2bf(va[u].z); pa.w = f2bf(va[u].w);
      pb.x = f2bf(vb[u].x); pb.y = f2bf(vb[u].y);
      pb.z = f2bf(vb[u].z); pb.w = f2bf(vb[u].w);
      *(ushort4*)&As[row][kc] = pa;
      *(ushort4*)&Bs[row][kc] = pb;
    }
    __syncthreads();                               // tiles ready

    // fragments: A lane: row=l&15 (+m*16+wr*64), k=(l>>4)*8+e
    const int fr = lane & 15, koff = (lane >> 4) * 8;
    bf16x8 a[4], bfr[4];
#pragma unroll
    for (int m = 0; m < 4; ++m)
      a[m] = *(const bf16x8*)&As[wr * 64 + m * 16 + fr][koff];
#pragma unroll
    for (int n = 0; n < 4; ++n)
      bfr[n] = *(const bf16x8*)&Bs[wc * 64 + n * 16 + fr][koff];
#pragma unroll
    for (int m = 0; m < 4; ++m)
#pragma unroll
      for (int n = 0; n < 4; ++n)
        acc[m][n] = __builtin_amdgcn_mfma_f32_16x16x32_bf16(
            a[m], bfr[n], acc[m][n], 0, 0, 0);
  }

  // C/D: col = lane&15, row = (lane>>4)*4 + reg
#pragma unroll
  for (int m = 0; m < 4; ++m) {
    const int row0 = s0 + wr * 64 + m * 16 + (lane >> 4) * 4;
#pragma unroll
    for (int n = 0; n < 4; ++n) {
      const int col = j0 + wc * 64 + n * 16 + (lane & 15);
#pragma unroll
      for (int r = 0; r < 4; ++r)
        xg[(size_t)(row0 + r) * G4 + col] = f2bf(acc[m][n][r] + bias[n]);
    }
  }
}

// =====================================================================
// Kernel 2: persistent cooperative scan, fence-free tagged-record sync.
// Wave w of block b owns unit j=b*8+w: its 4 gate rows (4x2048 weights,
// 128 fp32 regs/lane), butterfly allreduce, lanes 0-3 do activations,
// lane 0 updates c and publishes h. One barrier per step.
// =====================================================================
__global__ __launch_bounds__(TPB, 2) void lstm_scan(
    const unsigned short* __restrict__ xg, const float* __restrict__ Whh,
    const float* __restrict__ h0, const float* __restrict__ c0,
    float* __restrict__ out, unsigned long long* __restrict__ rec) {
  __shared__ float h_sh[2][2176];                  // 2048 + 4dw pad per 64

  const int b = blockIdx.x, t = threadIdx.x;
  const int lane = t & 63, wid = t >> 6;
  const int j = b * 8 + wid;                       // this wave's unit

  // weights: lane covers k-chunk [lane*32, lane*32+32) of 4 gate rows
  float w4[4][32];
#pragma unroll
  for (int g = 0; g < 4; ++g) {
    const float* wp = Whh + ((size_t)g * HDIM + j) * HDIM + lane * 32;
#pragma unroll
    for (int i = 0; i < 8; ++i) {
      const float4 v = *(const float4*)(wp + i * 4);
      w4[g][i*4+0] = v.x; w4[g][i*4+1] = v.y;
      w4[g][i*4+2] = v.z; w4[g][i*4+3] = v.w;
    }
  }
  float c_reg = (lane == 0) ? c0[j] : 0.f;
  const int hbase = lane * 32 + ((lane >> 1) << 2);   // swizzled dw base

  for (int ts = 0; ts < S_LEN; ++ts) {
    const int buf = ts & 1;
    // xg prefetch: lanes 0-3 load their gate's value (cached loads)
    float xgv = 0.f;
    if (lane < 4)
      xgv = bf2f(xg[(size_t)ts * G4 + (size_t)lane * HDIM + j]);

    if (ts == 0) {
#pragma unroll
      for (int kk = 0; kk < 4; ++kk) {
        const int idx = t + kk * 512;
        h_sh[0][idx + ((idx >> 6) << 2)] = h0[idx];
      }
    } else {
      const unsigned want = (unsigned)ts;
      const unsigned long long* slot = rec + (size_t)buf * HDIM;
      unsigned long long r0 = 0, r1 = 0, r2 = 0, r3 = 0;
      int d0 = 0, d1 = 0, d2 = 0, d3 = 0;
      for (;;) {
        if (!d0) { r0 = __hip_atomic_load(slot + t,        __ATOMIC_RELAXED, __HIP_MEMORY_SCOPE_AGENT); d0 = ((unsigned)(r0 >> 32) == want); }
        if (!d1) { r1 = __hip_atomic_load(slot + t + 512,  __ATOMIC_RELAXED, __HIP_MEMORY_SCOPE_AGENT); d1 = ((unsigned)(r1 >> 32) == want); }
        if (!d2) { r2 = __hip_atomic_load(slot + t + 1024, __ATOMIC_RELAXED, __HIP_MEMORY_SCOPE_AGENT); d2 = ((unsigned)(r2 >> 32) == want); }
        if (!d3) { r3 = __hip_atomic_load(slot + t + 1536, __ATOMIC_RELAXED, __HIP_MEMORY_SCOPE_AGENT); d3 = ((unsigned)(r3 >> 32) == want); }
        if (d0 & d1 & d2 & d3) break;
        __builtin_amdgcn_s_sleep(1);
      }
      const int i0 = t, i1 = t + 512, i2 = t + 1024, i3 = t + 1536;
      h_sh[buf][i0 + ((i0 >> 6) << 2)] = __uint_as_float((unsigned)r0);
      h_sh[buf][i1 + ((i1 >> 6) << 2)] = __uint_as_float((unsigned)r1);
      h_sh[buf][i2 + ((i2 >> 6) << 2)] = __uint_as_float((unsigned)r2);
      h_sh[buf][i3 + ((i3 >> 6) << 2)] = __uint_as_float((unsigned)r3);
    }
    __syncthreads();                               // h ready (only barrier)

    // 4 gate partial dots: 128 register FMAs vs LDS h (conflict-free)
    float a0 = 0.f, a1 = 0.f, a2 = 0.f, a3 = 0.f;
    const float4* h4 = (const float4*)&h_sh[buf][hbase];
#pragma unroll
    for (int i = 0; i < 8; ++i) {
      const float4 hv = h4[i];
      a0 = fmaf(w4[0][i*4+0], hv.x, a0); a0 = fmaf(w4[0][i*4+1], hv.y, a0);
      a0 = fmaf(w4[0][i*4+2], hv.z, a0); a0 = fmaf(w4[0][i*4+3], hv.w, a0);
      a1 = fmaf(w4[1][i*4+0], hv.x, a1); a1 = fmaf(w4[1][i*4+1], hv.y, a1);
      a1 = fmaf(w4[1][i*4+2], hv.z, a1); a1 = fmaf(w4[1][i*4+3], hv.w, a1);
      a2 = fmaf(w4[2][i*4+0], hv.x, a2); a2 = fmaf(w4[2][i*4+1], hv.y, a2);
      a2 = fmaf(w4[2][i*4+2], hv.z, a2); a2 = fmaf(w4[2][i*4+3], hv.w, a2);
      a3 = fmaf(w4[3][i*4+0], hv.x, a3); a3 = fmaf(w4[3][i*4+1], hv.y, a3);
      a3 = fmaf(w4[3][i*4+2], hv.z, a3); a3 = fmaf(w4[3][i*4+3], hv.w, a3);
    }
    // butterfly allreduce across the wave
#pragma unroll
    for (int m = 1; m < 64; m <<= 1) {
      a0 += __shfl_xor(a0, m);
      a1 += __shfl_xor(a1, m);
      a2 += __shfl_xor(a2, m);
      a3 += __shfl_xor(a3, m);
    }
    // lanes 0-3: activation of gate 'lane' (i,f use sigmoid; g tanh; o sigmoid)
    float sv = (lane == 0) ? a0 : (lane == 1) ? a1 : (lane == 2) ? a2 : a3;
    sv += xgv;
    const float av = (lane == 2) ? tanhf(sv) : 1.f / (1.f + __expf(-sv));
    const float iv = __shfl(av, 0);
    const float fv = __shfl(av, 1);
    const float gv = __shfl(av, 2);
    const float ov = __shfl(av, 3);
    if (lane == 0) {
      c_reg = fmaf(fv, c_reg, iv * gv);
      const float hn = ov * tanhf(c_reg);
      __hip_atomic_store(&rec[(size_t)(buf ^ 1) * HDIM + j],
                         pack_rec(hn, (unsigned)(ts + 1)),
                         __ATOMIC_RELAXED, __HIP_MEMORY_SCOPE_AGENT);
      out[(size_t)ts * HDIM + j] = hn;
    }
    // no trailing barrier: parity double-buffer + publish-gating make the
    // max inter-wave skew 1 step (a wave passes poll(ts+1) only after all
    // 8 waves of its own block published tag ts+1).
  }
}

// =====================================================================
extern "C" void kernel_launch(void* const* d_in, const int* in_sizes, int n_in,
                              void* d_out, int out_size, void* d_ws, size_t ws_size,
                              hipStream_t stream) {
  const float* x   = (const float*)d_in[0];
  const float* Wih = (const float*)d_in[1];
  const float* Whh = (const float*)d_in[2];
  const float* bih = (const float*)d_in[3];
  const float* bhh = (const float*)d_in[4];
  const float* h0  = (const float*)d_in[5];
  const float* c0  = (const float*)d_in[6];
  float* out = (float*)d_out;

  // ws layout: [0,32KB) tagged-record ring | [32KB, +64MB) xg bf16
  unsigned long long* rec = (unsigned long long*)d_ws;
  unsigned short* xg = (unsigned short*)((char*)d_ws + 32768);

  hipMemsetAsync(rec, 0, 2 * HDIM * sizeof(unsigned long long), stream);

  gemm_xg_mfma<<<dim3(2048), 256, 0, stream>>>(x, Wih, bih, bhh, xg);

  void* args[] = {(void*)&xg, (void*)&Whh, (void*)&h0,
                  (void*)&c0, (void*)&out, (void*)&rec};
  hipLaunchCooperativeKernel((void*)lstm_scan, dim3(NB), dim3(TPB),
                             args, 0, stream);
}

// Round 4
// 11623.983 us; speedup vs baseline: 6.7144x; 1.0996x over previous
//
#include <hip/hip_runtime.h>
#include <hip/hip_bf16.h>

#define S_LEN 4096
#define IDIM  2048
#define HDIM  2048
#define G4    8192
#define NB    256
#define TPB   512

typedef __attribute__((ext_vector_type(8))) short     bf16x8;
typedef __attribute__((ext_vector_type(4))) float     f32x4;

// ---- bf16 helpers ----
__device__ __forceinline__ unsigned short f2bf(float f) {
  unsigned u = __float_as_uint(f);
  unsigned r = (u + 0x7FFFu + ((u >> 16) & 1u)) >> 16;   // RNE
  return (unsigned short)r;
}
__device__ __forceinline__ float bf2f(unsigned short h) {
  return __uint_as_float(((unsigned)h) << 16);
}

// =====================================================================
// Kernel 1: xg = x·W_ihᵀ + b_ih + b_hh, bf16 MFMA. (proven, ~0.1 ms)
// =====================================================================
#define BM 128
#define BKK 32
#define LDK 40

__global__ __launch_bounds__(256) void gemm_xg_mfma(
    const float* __restrict__ x, const float* __restrict__ Wih,
    const float* __restrict__ bih, const float* __restrict__ bhh,
    unsigned short* __restrict__ xg) {
  __shared__ unsigned short As[BM][LDK];
  __shared__ unsigned short Bs[BM][LDK];

  const int t = threadIdx.x;
  const int lane = t & 63, wid = t >> 6;
  const int wr = wid >> 1, wc = wid & 1;

  int bid = ((int)blockIdx.x & 7) * 256 + ((int)blockIdx.x >> 3);
  const int s0 = (bid >> 6) * BM;
  const int j0 = (bid & 63) * BM;

  f32x4 acc[4][4] = {};

  float bias[4];
#pragma unroll
  for (int n = 0; n < 4; ++n) {
    const int col = j0 + wc * 64 + n * 16 + (lane & 15);
    bias[n] = bih[col] + bhh[col];
  }

  for (int k0 = 0; k0 < IDIM; k0 += BKK) {
    float4 va[4], vb[4];
#pragma unroll
    for (int u = 0; u < 4; ++u) {
      const int f = t + 256 * u;
      const int row = f >> 3, kc = (f & 7) * 4;
      va[u] = *(const float4*)&x  [(size_t)(s0 + row) * IDIM + k0 + kc];
      vb[u] = *(const float4*)&Wih[(size_t)(j0 + row) * IDIM + k0 + kc];
    }
    __syncthreads();
#pragma unroll
    for (int u = 0; u < 4; ++u) {
      const int f = t + 256 * u;
      const int row = f >> 3, kc = (f & 7) * 4;
      ushort4 pa, pb;
      pa.x = f2bf(va[u].x); pa.y = f2bf(va[u].y);
      pa.z = f2bf(va[u].z); pa.w = f2bf(va[u].w);
      pb.x = f2bf(vb[u].x); pb.y = f2bf(vb[u].y);
      pb.z = f2bf(vb[u].z); pb.w = f2bf(vb[u].w);
      *(ushort4*)&As[row][kc] = pa;
      *(ushort4*)&Bs[row][kc] = pb;
    }
    __syncthreads();

    const int fr = lane & 15, koff = (lane >> 4) * 8;
    bf16x8 a[4], bfr[4];
#pragma unroll
    for (int m = 0; m < 4; ++m)
      a[m] = *(const bf16x8*)&As[wr * 64 + m * 16 + fr][koff];
#pragma unroll
    for (int n = 0; n < 4; ++n)
      bfr[n] = *(const bf16x8*)&Bs[wc * 64 + n * 16 + fr][koff];
#pragma unroll
    for (int m = 0; m < 4; ++m)
#pragma unroll
      for (int n = 0; n < 4; ++n)
        acc[m][n] = __builtin_amdgcn_mfma_f32_16x16x32_bf16(
            a[m], bfr[n], acc[m][n], 0, 0, 0);
  }

#pragma unroll
  for (int m = 0; m < 4; ++m) {
    const int row0 = s0 + wr * 64 + m * 16 + (lane >> 4) * 4;
#pragma unroll
    for (int n = 0; n < 4; ++n) {
      const int col = j0 + wc * 64 + n * 16 + (lane & 15);
#pragma unroll
      for (int r = 0; r < 4; ++r)
        xg[(size_t)(row0 + r) * G4 + col] = f2bf(acc[m][n][r] + bias[n]);
    }
  }
}

// =====================================================================
// Kernel 2: persistent scan — flag-then-bulk-read sync.
//  publish: 8 relaxed-atomic fp32 stores into out[ts] (write-through),
//           __syncthreads (drains vmcnt per wave), flags[b]=ts+1.
//  acquire: wave0 polls the 256 monotonic flags (re-load only missing),
//           barrier, then whole block reads out[ts-1] ONCE (8B atomic
//           loads, wave-coalesced). out is a 4096-deep ring: no reuse,
//           no overwrite hazard, no tags.
// =====================================================================
__global__ __launch_bounds__(TPB, 2) void lstm_scan(
    const unsigned short* __restrict__ xg, const float* __restrict__ Whh,
    const float* __restrict__ h0, const float* __restrict__ c0,
    float* __restrict__ out, unsigned* __restrict__ flags) {
  __shared__ __align__(16) float h_sh[2][2176];   // 2048 + 4dw pad per 64

  const int b = blockIdx.x, t = threadIdx.x;
  const int lane = t & 63, wid = t >> 6;
  const int j = b * 8 + wid;                      // this wave's unit

  // weights: lane covers k-chunk [lane*32, lane*32+32) of unit j's 4 gate rows
  float w4[4][32];
#pragma unroll
  for (int g = 0; g < 4; ++g) {
    const float* wp = Whh + ((size_t)g * HDIM + j) * HDIM + lane * 32;
#pragma unroll
    for (int i = 0; i < 8; ++i) {
      const float4 v = *(const float4*)(wp + i * 4);
      w4[g][i*4+0] = v.x; w4[g][i*4+1] = v.y;
      w4[g][i*4+2] = v.z; w4[g][i*4+3] = v.w;
    }
  }
  float c_reg = (lane == 0) ? c0[j] : 0.f;
  const int hbase = lane * 32 + ((lane >> 1) << 2);  // swizzled dw base

  for (int ts = 0; ts < S_LEN; ++ts) {
    const int buf = ts & 1;
    // xg prefetch (lanes 0-3: this unit's 4 gate pre-activations)
    float xgv = 0.f;
    if (lane < 4)
      xgv = bf2f(xg[(size_t)ts * G4 + (size_t)lane * HDIM + j]);

    if (ts == 0) {
#pragma unroll
      for (int kk = 0; kk < 4; ++kk) {
        const int idx = t + kk * 512;
        h_sh[0][idx + ((idx >> 6) << 2)] = h0[idx];
      }
      __syncthreads();
    } else {
      // ---- wave 0: poll 256 monotonic flags (1 KB; reload only missing) ----
      if (wid == 0) {
        const unsigned want = (unsigned)ts;
        unsigned f0 = 0, f1 = 0, f2 = 0, f3 = 0;
        for (;;) {
          if (f0 < want) f0 = __hip_atomic_load(&flags[lane],       __ATOMIC_RELAXED, __HIP_MEMORY_SCOPE_AGENT);
          if (f1 < want) f1 = __hip_atomic_load(&flags[lane +  64], __ATOMIC_RELAXED, __HIP_MEMORY_SCOPE_AGENT);
          if (f2 < want) f2 = __hip_atomic_load(&flags[lane + 128], __ATOMIC_RELAXED, __HIP_MEMORY_SCOPE_AGENT);
          if (f3 < want) f3 = __hip_atomic_load(&flags[lane + 192], __ATOMIC_RELAXED, __HIP_MEMORY_SCOPE_AGENT);
          if (f0 >= want && f1 >= want && f2 >= want && f3 >= want) break;
          __builtin_amdgcn_s_sleep(1);
        }
      }
      __syncthreads();                            // flags seen by all waves
      // ---- bulk read h_{ts-1} once: thread t reads 8B at dw 2t ----
      const float* src = out + (size_t)(ts - 1) * HDIM;
      const unsigned long long r0 = __hip_atomic_load(
          (const unsigned long long*)(src) + t,       __ATOMIC_RELAXED, __HIP_MEMORY_SCOPE_AGENT);
      const unsigned long long r1 = __hip_atomic_load(
          (const unsigned long long*)(src) + t + 512, __ATOMIC_RELAXED, __HIP_MEMORY_SCOPE_AGENT);
      const int i0 = t * 2, i1 = t * 2 + 1024;
      h_sh[buf][i0     + ((i0 >> 6) << 2)] = __uint_as_float((unsigned)(r0));
      h_sh[buf][i0 + 1 + ((i0 >> 6) << 2)] = __uint_as_float((unsigned)(r0 >> 32));
      h_sh[buf][i1     + ((i1 >> 6) << 2)] = __uint_as_float((unsigned)(r1));
      h_sh[buf][i1 + 1 + ((i1 >> 6) << 2)] = __uint_as_float((unsigned)(r1 >> 32));
      __syncthreads();                            // h ready
    }

    // ---- 4 gate partial dots: 128 register FMAs vs LDS h ----
    float a0 = 0.f, a1 = 0.f, a2 = 0.f, a3 = 0.f;
    const float4* h4 = (const float4*)&h_sh[buf][hbase];
#pragma unroll
    for (int i = 0; i < 8; ++i) {
      const float4 hv = h4[i];
      a0 = fmaf(w4[0][i*4+0], hv.x, a0); a0 = fmaf(w4[0][i*4+1], hv.y, a0);
      a0 = fmaf(w4[0][i*4+2], hv.z, a0); a0 = fmaf(w4[0][i*4+3], hv.w, a0);
      a1 = fmaf(w4[1][i*4+0], hv.x, a1); a1 = fmaf(w4[1][i*4+1], hv.y, a1);
      a1 = fmaf(w4[1][i*4+2], hv.z, a1); a1 = fmaf(w4[1][i*4+3], hv.w, a1);
      a2 = fmaf(w4[2][i*4+0], hv.x, a2); a2 = fmaf(w4[2][i*4+1], hv.y, a2);
      a2 = fmaf(w4[2][i*4+2], hv.z, a2); a2 = fmaf(w4[2][i*4+3], hv.w, a2);
      a3 = fmaf(w4[3][i*4+0], hv.x, a3); a3 = fmaf(w4[3][i*4+1], hv.y, a3);
      a3 = fmaf(w4[3][i*4+2], hv.z, a3); a3 = fmaf(w4[3][i*4+3], hv.w, a3);
    }
    // butterfly allreduce across the wave
#pragma unroll
    for (int m = 1; m < 64; m <<= 1) {
      a0 += __shfl_xor(a0, m);
      a1 += __shfl_xor(a1, m);
      a2 += __shfl_xor(a2, m);
      a3 += __shfl_xor(a3, m);
    }
    // lanes 0-3: activation of gate 'lane'
    float sv = (lane == 0) ? a0 : (lane == 1) ? a1 : (lane == 2) ? a2 : a3;
    sv += xgv;
    const float av = (lane == 2) ? tanhf(sv) : 1.f / (1.f + __expf(-sv));
    const float iv = __shfl(av, 0);
    const float fv = __shfl(av, 1);
    const float gv = __shfl(av, 2);
    const float ov = __shfl(av, 3);
    if (lane == 0) {
      c_reg = fmaf(fv, c_reg, iv * gv);
      const float hn = ov * tanhf(c_reg);
      // publication IS the output write (write-through to LLC)
      __hip_atomic_store(&out[(size_t)ts * HDIM + j], hn,
                         __ATOMIC_RELAXED, __HIP_MEMORY_SCOPE_AGENT);
    }
    __syncthreads();         // every wave: vmcnt(0) drain before s_barrier
    if (t == 0)
      __hip_atomic_store(&flags[b], (unsigned)(ts + 1),
                         __ATOMIC_RELAXED, __HIP_MEMORY_SCOPE_AGENT);
  }
}

// =====================================================================
extern "C" void kernel_launch(void* const* d_in, const int* in_sizes, int n_in,
                              void* d_out, int out_size, void* d_ws, size_t ws_size,
                              hipStream_t stream) {
  const float* x   = (const float*)d_in[0];
  const float* Wih = (const float*)d_in[1];
  const float* Whh = (const float*)d_in[2];
  const float* bih = (const float*)d_in[3];
  const float* bhh = (const float*)d_in[4];
  const float* h0  = (const float*)d_in[5];
  const float* c0  = (const float*)d_in[6];
  float* out = (float*)d_out;

  // ws layout: [0,1KB) flags | [32KB, +64MB) xg bf16
  unsigned* flags = (unsigned*)d_ws;
  unsigned short* xg = (unsigned short*)((char*)d_ws + 32768);

  hipMemsetAsync(flags, 0, NB * sizeof(unsigned), stream);

  gemm_xg_mfma<<<dim3(2048), 256, 0, stream>>>(x, Wih, bih, bhh, xg);

  void* args[] = {(void*)&xg, (void*)&Whh, (void*)&h0,
                  (void*)&c0, (void*)&out, (void*)&flags};
  hipLaunchCooperativeKernel((void*)lstm_scan, dim3(NB), dim3(TPB),
                             args, 0, stream);
}